// Round 5
// baseline (228.350 us; speedup 1.0000x reference)
//
#include <hip/hip_runtime.h>
#include <hip/hip_cooperative_groups.h>

namespace cg = cooperative_groups;

// GatherRouter: top-2 MoE combine.
// tags[p] is a permutation of [0,T) -> out[t] = data[0][inv0[t]] + data[1][inv1[t]].
// Single cooperative kernel: phase A builds inverse permutations (tiny),
// grid.sync(), phase B gathers. Loads are regular (cached — R3 showed nt
// loads are a 4x latency disaster); stores nontemporal (output never re-read).

typedef float f32x4 __attribute__((ext_vector_type(4)));

#define NBLOCKS  2048   // 8 blocks/CU on 256 CUs -> co-resident at 100% occupancy
#define NTHREADS 256

__global__ __launch_bounds__(NTHREADS, 8)
void fused_router_kernel(const f32x4* __restrict__ data,
                         const int*   __restrict__ tags,
                         int*         __restrict__ inv,
                         f32x4*       __restrict__ out,
                         int T, int D4, int N) {
    cg::grid_group grid = cg::this_grid();

    // ---- Phase A: inverse permutations (N = 2T entries, trivial) ----
    int gtid = blockIdx.x * NTHREADS + threadIdx.x;
    if (gtid < N) {
        int p   = (gtid >= T) ? 1 : 0;    // flow index (P == 2)
        int pos = gtid - p * T;           // position within flow
        inv[p * T + tags[gtid]] = pos;    // inverse permutation
    }

    __threadfence();
    grid.sync();

    // ---- Phase B: out[row] = data0[inv0[row]] + data1[inv1[row]] ----
    int c = threadIdx.x;
    for (int row = blockIdx.x; row < T; row += NBLOCKS) {
        int i0 = inv[row];
        int i1 = inv[T + row];
        const f32x4* a = data + (size_t)i0 * D4;
        const f32x4* b = data + ((size_t)T + (size_t)i1) * D4;
        f32x4* o = out + (size_t)row * D4;

        if (D4 == 2 * NTHREADS) {
            // Fast path (D==2048): all 4 loads issued before any use.
            f32x4 va0 = a[c];
            f32x4 vb0 = b[c];
            f32x4 va1 = a[c + NTHREADS];
            f32x4 vb1 = b[c + NTHREADS];
            __builtin_nontemporal_store(va0 + vb0, o + c);
            __builtin_nontemporal_store(va1 + vb1, o + c + NTHREADS);
        } else {
            for (int cc = c; cc < D4; cc += NTHREADS) {
                f32x4 va = a[cc];
                f32x4 vb = b[cc];
                __builtin_nontemporal_store(va + vb, o + cc);
            }
        }
    }
}

extern "C" void kernel_launch(void* const* d_in, const int* in_sizes, int n_in,
                              void* d_out, int out_size, void* d_ws, size_t ws_size,
                              hipStream_t stream) {
    const f32x4* data = (const f32x4*)d_in[0];   // [P, T, D] f32
    const int*   tags = (const int*)d_in[1];     // [P, T]
    // d_in[2] = load (scalar) — not needed; shapes derived from sizes.

    const int N  = in_sizes[1];          // P*T = 16384
    const int D  = in_sizes[0] / N;      // 2048
    int T        = out_size / D;         // 8192
    int D4       = D / 4;                // 512
    int Nmut     = N;

    int* inv = (int*)d_ws;               // P*T ints = 64 KB scratch

    f32x4* out = (f32x4*)d_out;
    void* args[] = {(void*)&data, (void*)&tags, (void*)&inv, (void*)&out,
                    (void*)&T, (void*)&D4, (void*)&Nmut};
    hipLaunchCooperativeKernel((void*)fused_router_kernel,
                               dim3(NBLOCKS), dim3(NTHREADS),
                               args, 0, stream);
}

// Round 6
// 39.416 us; speedup vs baseline: 5.7934x; 5.7934x over previous
//
#include <hip/hip_runtime.h>

// GatherRouter: top-2 MoE combine.
// tags[p] is a permutation of [0,T) -> out[t] = data[0][inv0[t]] + data[1][inv1[t]].
// Two kernels (R4 structure, 38.9us proven; cooperative fusion is 6x WORSE
// because grid.sync() costs ~200us at 2048 blocks on 8 XCDs).
// This round: 2 rows per block -> 8 loads (128B) in flight per thread.

typedef float f32x4 __attribute__((ext_vector_type(4)));

__global__ void build_inverse_kernel(const int* __restrict__ tags,
                                     int* __restrict__ inv,
                                     int T, int N) {
    int i = blockIdx.x * blockDim.x + threadIdx.x;
    if (i < N) {
        int p = (i >= T) ? 1 : 0;   // flow index (P == 2)
        int pos = i - p * T;        // position within flow
        inv[p * T + tags[i]] = pos; // inverse permutation
    }
}

// One block of 256 per TWO output rows; D4 float4 per row (D4 == 512 here).
__global__ __launch_bounds__(256)
void gather_add_kernel(const f32x4* __restrict__ data,
                       const int* __restrict__ inv,
                       f32x4* __restrict__ out,
                       int T, int D4) {
    int row0 = blockIdx.x * 2;
    int row1 = row0 + 1;
    int c = threadIdx.x;

    if (D4 == 2 * 256) {
        // Fast path (D==2048): 8 loads issued before any use (128B/thread MLP).
        int i0a = inv[row0];
        int i0b = inv[T + row0];
        int i1a = inv[row1];
        int i1b = inv[T + row1];
        const f32x4* a0 = data + (size_t)i0a * D4;
        const f32x4* b0 = data + ((size_t)T + (size_t)i0b) * D4;
        const f32x4* a1 = data + (size_t)i1a * D4;
        const f32x4* b1 = data + ((size_t)T + (size_t)i1b) * D4;
        f32x4* o0 = out + (size_t)row0 * D4;
        f32x4* o1 = out + (size_t)row1 * D4;

        f32x4 va00 = a0[c];
        f32x4 vb00 = b0[c];
        f32x4 va01 = a0[c + 256];
        f32x4 vb01 = b0[c + 256];
        f32x4 va10 = a1[c];
        f32x4 vb10 = b1[c];
        f32x4 va11 = a1[c + 256];
        f32x4 vb11 = b1[c + 256];
        __builtin_nontemporal_store(va00 + vb00, o0 + c);
        __builtin_nontemporal_store(va01 + vb01, o0 + c + 256);
        __builtin_nontemporal_store(va10 + vb10, o1 + c);
        __builtin_nontemporal_store(va11 + vb11, o1 + c + 256);
    } else {
        for (int r = row0; r <= row1; ++r) {
            int ia = inv[r];
            int ib = inv[T + r];
            const f32x4* a = data + (size_t)ia * D4;
            const f32x4* b = data + ((size_t)T + (size_t)ib) * D4;
            f32x4* o = out + (size_t)r * D4;
            for (int cc = c; cc < D4; cc += 256) {
                f32x4 va = a[cc];
                f32x4 vb = b[cc];
                __builtin_nontemporal_store(va + vb, o + cc);
            }
        }
    }
}

extern "C" void kernel_launch(void* const* d_in, const int* in_sizes, int n_in,
                              void* d_out, int out_size, void* d_ws, size_t ws_size,
                              hipStream_t stream) {
    const f32x4* data = (const f32x4*)d_in[0];   // [P, T, D] f32
    const int*   tags = (const int*)d_in[1];     // [P, T]
    // d_in[2] = load (scalar) — not needed; shapes derived from sizes.

    const int N  = in_sizes[1];          // P*T = 16384
    const int D  = in_sizes[0] / N;      // 2048
    const int T  = out_size / D;         // 8192
    const int D4 = D / 4;                // 512

    int* inv = (int*)d_ws;               // P*T ints = 64 KB scratch

    build_inverse_kernel<<<(N + 255) / 256, 256, 0, stream>>>(tags, inv, T, N);
    gather_add_kernel<<<T / 2, 256, 0, stream>>>(data, inv, (f32x4*)d_out, T, D4);
}